// Round 5
// baseline (254.467 us; speedup 1.0000x reference)
//
#include <hip/hip_runtime.h>
#include <hip/hip_bf16.h>
#include <stdint.h>

#define KD 512
#define OD 8
#define SZ (KD*KD*OD)       // 2097152 elements per A/B/C tensor
#define NR 4096             // GEMM dim: rows (j*8+x), cols (i*8+y)

typedef short v8s __attribute__((ext_vector_type(8)));
typedef float v4f __attribute__((ext_vector_type(4)));

#define GLOBAL_AS __attribute__((address_space(1)))
#define LDS_AS __attribute__((address_space(3)))

static __device__ __forceinline__ unsigned short f2bf(float f) {
    union { float f; unsigned int u; } v; v.f = f;
    unsigned int u = v.u;
    unsigned int r = u + 0x7FFF + ((u >> 16) & 1);   // RNE
    return (unsigned short)(r >> 16);
}

static __device__ __forceinline__ void async16(const unsigned short* g, unsigned short* l) {
    __builtin_amdgcn_global_load_lds((const GLOBAL_AS void*)g, (LDS_AS void*)l, 16, 0, 0);
}

// ---------------------------------------------------------------------------
// Pack into one-GEMM layout (bf16, k-contiguous):
//   Aop[j*8+x][k] = A[j,k,x]*Pb[j]*Pc[k]   (blocks 0..511, one j each)
//   Bop[i*8+y][k] = B[k,i,y]*Pa[i]         (blocks 512..639, 32 rows each)
// Block 0 zeroes probs partials (8x512) + counter (ws poisoned 0xAA per call).
// ---------------------------------------------------------------------------
__global__ __launch_bounds__(256) void pack_kernel(const float* __restrict__ yp,
                                                   unsigned short* __restrict__ Aop,
                                                   unsigned short* __restrict__ Bop,
                                                   float* __restrict__ part,
                                                   unsigned int* __restrict__ counter) {
    __shared__ unsigned short lds[32 * 520];   // B: 32 rows x 520; A uses 8 x 520
    const float* Pa = yp;
    const float* Pb = yp + KD;
    const float* Pc = yp + 2 * KD;
    const float* A  = yp + 3 * KD;
    const float* B  = A + SZ;
    const int b = blockIdx.x;
    const int t = threadIdx.x;

    if (b == 0) {
        #pragma unroll
        for (int i = 0; i < 16; ++i) part[t + i * 256] = 0.f;
        if (t == 0) *counter = 0u;
    }

    if (b < 512) {
        // ---- A-pack: j = b. thread t handles k = 2t, 2t+1 (x fast in src) ----
        const int j = b;
        const float pb = Pb[j];
        const int k2 = 2 * t;
        const float4* src = (const float4*)(A + (size_t)j * 4096 + (size_t)k2 * 8);
        float av[16];
        ((float4*)av)[0] = src[0];
        ((float4*)av)[1] = src[1];
        ((float4*)av)[2] = src[2];
        ((float4*)av)[3] = src[3];
        const float s0 = pb * Pc[k2];
        const float s1 = pb * Pc[k2 + 1];
        #pragma unroll
        for (int x = 0; x < 8; ++x) {
            ushort2 wv;
            wv.x = f2bf(av[x] * s0);
            wv.y = f2bf(av[8 + x] * s1);
            *(ushort2*)&lds[x * 520 + k2] = wv;
        }
        __syncthreads();
        // write 8 rows x 512 k, coalesced uint4
        const int r = t >> 5;        // 0..7 = x
        const int c = t & 31;
        unsigned short* dst = Aop + ((size_t)j * 8 + r) * KD;
        *(uint4*)&dst[c * 8]       = *(const uint4*)&lds[r * 520 + c * 8];
        *(uint4*)&dst[c * 8 + 256] = *(const uint4*)&lds[r * 520 + c * 8 + 256];
    } else {
        // ---- B-pack: rows r0..r0+31 (r = i*8+y), transpose [k][r] -> [r][k] ----
        const int r0 = (b - 512) * 32;
        const int r4 = (t & 7) * 4;
        const int kq = t >> 3;                  // 0..31
        const float pa = Pa[(r0 + r4) >> 3];
        #pragma unroll
        for (int p = 0; p < 16; ++p) {
            const int k = p * 32 + kq;
            const float4 bv = *(const float4*)(B + (size_t)k * 4096 + r0 + r4);
            lds[(r4 + 0) * 520 + k] = f2bf(bv.x * pa);
            lds[(r4 + 1) * 520 + k] = f2bf(bv.y * pa);
            lds[(r4 + 2) * 520 + k] = f2bf(bv.z * pa);
            lds[(r4 + 3) * 520 + k] = f2bf(bv.w * pa);
        }
        __syncthreads();
        const int r = t >> 3;                   // 0..31
        const int c0 = t & 7;
        unsigned short* dst = Bop + (size_t)(r0 + r) * KD;
        #pragma unroll
        for (int p = 0; p < 8; ++p) {
            const int c = c0 + p * 8;
            *(uint4*)&dst[c * 8] = *(const uint4*)&lds[r * 520 + c * 8];
        }
    }
}

// ---------------------------------------------------------------------------
// One 4096x4096x512 bf16 GEMM (1024 blocks of 128x128, BK=64) + fused
// C-contraction epilogue (8 KB C patch per block, read once globally) +
// last-block finalize. Block swizzle: XCD (bid&7) sees 8 bm x 16 bn ~ 3 MB.
// D-tile rows = (j*8+x), cols = (i*8+y); probs[x,y,z] += T[M,N]*C[i,j,z].
// ---------------------------------------------------------------------------
__global__ __launch_bounds__(256, 3) void gemm_kernel(
        const float* __restrict__ yp, const float* __restrict__ yt,
        const unsigned short* __restrict__ Aop,
        const unsigned short* __restrict__ Bop,
        float* __restrict__ part, unsigned int* __restrict__ counter,
        float* __restrict__ out) {

    __shared__ union {
        unsigned short stage[2][128 * 64];   // 32 KB
        float red[4 * 512];                  // 8 KB per-wave output partials
    } sh;
    __shared__ int is_last;
    __shared__ float kred[4];

    const int bid = blockIdx.x;
    const int s8 = bid & 7;
    const int rr_ = bid >> 3;
    const int bm = ((s8 & 3) << 3) | (rr_ & 7);    // 0..31
    const int bn = ((s8 >> 2) << 4) | (rr_ >> 3);  // 0..31
    const int m0 = bm * 128;
    const int n0 = bn * 128;

    const int t = threadIdx.x;
    const int w = t >> 6;
    const int l = t & 63;
    const int wm = w >> 1, wn = w & 1;
    const int lm = l & 15, quad = l >> 4;
    const int row8 = l >> 3, ch = l & 7;

    v4f acc[4][4];
    #pragma unroll
    for (int mt = 0; mt < 4; ++mt)
        #pragma unroll
        for (int nt = 0; nt < 4; ++nt)
            acc[mt][nt] = (v4f){0.f, 0.f, 0.f, 0.f};

    for (int kt = 0; kt < 8; ++kt) {
        const int kb = kt * 64;
        #pragma unroll
        for (int a = 0; a < 4; ++a) {
            const int rowA = w * 32 + a * 8;
            async16(Aop + (size_t)(m0 + rowA + row8) * KD + kb + ch * 8,
                    &sh.stage[0][rowA * 64]);
            async16(Bop + (size_t)(n0 + rowA + row8) * KD + kb + ch * 8,
                    &sh.stage[1][rowA * 64]);
        }
        __syncthreads();

        #pragma unroll
        for (int ss = 0; ss < 2; ++ss) {
            v8s aF[4], bF[4];
            #pragma unroll
            for (int mt = 0; mt < 4; ++mt)
                aF[mt] = *(const v8s*)&sh.stage[0][(wm * 64 + mt * 16 + lm) * 64 + ss * 32 + quad * 8];
            #pragma unroll
            for (int nt = 0; nt < 4; ++nt)
                bF[nt] = *(const v8s*)&sh.stage[1][(wn * 64 + nt * 16 + lm) * 64 + ss * 32 + quad * 8];
            #pragma unroll
            for (int mt = 0; mt < 4; ++mt)
                #pragma unroll
                for (int nt = 0; nt < 4; ++nt)
                    acc[mt][nt] = __builtin_amdgcn_mfma_f32_16x16x32_bf16(
                        aF[mt], bF[nt], acc[mt][nt], 0, 0, 0);
        }
        __syncthreads();
    }

    // ---- epilogue ----
    // M = m0 + wm*64 + mt*16 + quad*4 + rr -> x=(quad&1)*4+rr, j=M>>3
    // N = n0 + wn*64 + nt*16 + lm         -> y=lm&7,          i=N>>3
    const float* Cbase = yp + 3 * KD + 2 * (size_t)SZ;
    const int jA = bm * 16 + wm * 8 + (quad >> 1);   // + mt*2
    const int iA = bn * 16 + wn * 8 + (lm >> 3);     // + nt*2
    const int xpar = quad & 1;
    const int yv = lm & 7;

    #pragma unroll
    for (int zh = 0; zh < 2; ++zh) {
        v4f pacc[4];
        #pragma unroll
        for (int rr = 0; rr < 4; ++rr) pacc[rr] = (v4f){0.f, 0.f, 0.f, 0.f};

        #pragma unroll
        for (int mt = 0; mt < 4; ++mt) {
            #pragma unroll
            for (int nt = 0; nt < 4; ++nt) {
                const int i = iA + nt * 2;
                const int j = jA + mt * 2;
                const float4 cv = *(const float4*)(Cbase + (size_t)i * 4096 + j * 8 + zh * 4);
                #pragma unroll
                for (int rr = 0; rr < 4; ++rr) {
                    const float tv = acc[mt][nt][rr];
                    pacc[rr][0] += tv * cv.x;
                    pacc[rr][1] += tv * cv.y;
                    pacc[rr][2] += tv * cv.z;
                    pacc[rr][3] += tv * cv.w;
                }
            }
        }
        // reduce over i-bit (lane^8) and j-bit (lane^32)
        #pragma unroll
        for (int rr = 0; rr < 4; ++rr) {
            #pragma unroll
            for (int q = 0; q < 4; ++q) {
                float v = pacc[rr][q];
                v += __shfl_xor(v, 8, 64);
                v += __shfl_xor(v, 32, 64);
                pacc[rr][q] = v;
            }
        }
        if ((l & 40) == 0) {   // rep lanes: bits 3,5 clear
            #pragma unroll
            for (int rr = 0; rr < 4; ++rr) {
                const int x = xpar * 4 + rr;
                *(float4*)&sh.red[w * 512 + x * 64 + yv * 8 + zh * 4] =
                    make_float4(pacc[rr][0], pacc[rr][1], pacc[rr][2], pacc[rr][3]);
            }
        }
    }
    __syncthreads();
    #pragma unroll
    for (int h = 0; h < 2; ++h) {
        const int o = t + h * 256;
        const float sv = sh.red[o] + sh.red[512 + o] + sh.red[1024 + o] + sh.red[1536 + o];
        atomicAdd(&part[s8 * 512 + o], sv);
    }

    // ---- last-block finalize ----
    __threadfence();
    __syncthreads();
    if (t == 0) {
        const unsigned int old = atomicAdd(counter, 1u);
        is_last = (old == 1023u);
    }
    __syncthreads();
    if (is_last) {
        float term = 0.f;
        #pragma unroll
        for (int h = 0; h < 2; ++h) {
            const int o = t + h * 256;
            float p = 0.f;
            #pragma unroll
            for (int p8 = 0; p8 < 8; ++p8)
                p += atomicAdd(&part[p8 * 512 + o], 0.0f);   // coherent read
            out[1 + o] = p;
            const float ytv = yt[o];
            const float pc = fminf(fmaxf(p, 1e-10f), 1.0f);
            term += ytv * (logf(ytv + 1e-10f) - logf(pc));
        }
        for (int off = 32; off > 0; off >>= 1)
            term += __shfl_xor(term, off, 64);
        if (l == 0) kred[w] = term;
        __syncthreads();
        if (t == 0)
            out[0] = kred[0] + kred[1] + kred[2] + kred[3];
    }
}

extern "C" void kernel_launch(void* const* d_in, const int* in_sizes, int n_in,
                              void* d_out, int out_size, void* d_ws, size_t ws_size,
                              hipStream_t stream) {
    const float* yp = (const float*)d_in[0];
    const float* yt = (const float*)d_in[1];
    float* out = (float*)d_out;

    unsigned short* Aop = (unsigned short*)d_ws;               // 4 MB
    unsigned short* Bop = Aop + (size_t)NR * KD;               // 4 MB
    float* part = (float*)(Bop + (size_t)NR * KD);             // 8x512 floats
    unsigned int* counter = (unsigned int*)(part + 8 * 512);

    pack_kernel<<<640, 256, 0, stream>>>(yp, Aop, Bop, part, counter);
    gemm_kernel<<<1024, 256, 0, stream>>>(yp, yt, Aop, Bop, part, counter, out);
}

// Round 6
// 196.448 us; speedup vs baseline: 1.2953x; 1.2953x over previous
//
#include <hip/hip_runtime.h>
#include <hip/hip_bf16.h>
#include <stdint.h>

#define KD 512
#define OD 8
#define SZ (KD*KD*OD)       // 2097152 elements per A/B/C tensor
#define NR 4096             // GEMM dim: rows (j*8+x), cols (i*8+y)

typedef short v8s __attribute__((ext_vector_type(8)));
typedef float v4f __attribute__((ext_vector_type(4)));

#define GLOBAL_AS __attribute__((address_space(1)))
#define LDS_AS __attribute__((address_space(3)))

static __device__ __forceinline__ unsigned short f2bf(float f) {
    union { float f; unsigned int u; } v; v.f = f;
    unsigned int u = v.u;
    unsigned int r = u + 0x7FFF + ((u >> 16) & 1);   // RNE
    return (unsigned short)(r >> 16);
}

static __device__ __forceinline__ void async16(const unsigned short* g, unsigned short* l) {
    __builtin_amdgcn_global_load_lds((const GLOBAL_AS void*)g, (LDS_AS void*)l, 16, 0, 0);
}

// ---------------------------------------------------------------------------
// Pack into one-GEMM layout (bf16, k-contiguous):
//   Aop[j*8+x][k] = A[j,k,x]*Pb[j]*Pc[k]   (blocks 0..511, one j each)
//   Bop[i*8+y][k] = B[k,i,y]*Pa[i]         (blocks 512..639, 32 rows each)
// Block 0 zeroes probs partials (8x512) + counter (ws poisoned 0xAA per call).
// ---------------------------------------------------------------------------
__global__ __launch_bounds__(256) void pack_kernel(const float* __restrict__ yp,
                                                   unsigned short* __restrict__ Aop,
                                                   unsigned short* __restrict__ Bop,
                                                   float* __restrict__ part,
                                                   unsigned int* __restrict__ counter) {
    __shared__ unsigned short lds[32 * 520];
    const float* Pa = yp;
    const float* Pb = yp + KD;
    const float* Pc = yp + 2 * KD;
    const float* A  = yp + 3 * KD;
    const float* B  = A + SZ;
    const int b = blockIdx.x;
    const int t = threadIdx.x;

    if (b == 0) {
        #pragma unroll
        for (int i = 0; i < 16; ++i) part[t + i * 256] = 0.f;
        if (t == 0) *counter = 0u;
    }

    if (b < 512) {
        // ---- A-pack: j = b. thread t handles k = 2t, 2t+1 (x fast in src) ----
        const int j = b;
        const float pb = Pb[j];
        const int k2 = 2 * t;
        const float4* src = (const float4*)(A + (size_t)j * 4096 + (size_t)k2 * 8);
        float av[16];
        ((float4*)av)[0] = src[0];
        ((float4*)av)[1] = src[1];
        ((float4*)av)[2] = src[2];
        ((float4*)av)[3] = src[3];
        const float s0 = pb * Pc[k2];
        const float s1 = pb * Pc[k2 + 1];
        #pragma unroll
        for (int x = 0; x < 8; ++x) {
            ushort2 wv;
            wv.x = f2bf(av[x] * s0);
            wv.y = f2bf(av[8 + x] * s1);
            *(ushort2*)&lds[x * 520 + k2] = wv;
        }
        __syncthreads();
        const int r = t >> 5;        // 0..7 = x
        const int c = t & 31;
        unsigned short* dst = Aop + ((size_t)j * 8 + r) * KD;
        *(uint4*)&dst[c * 8]       = *(const uint4*)&lds[r * 520 + c * 8];
        *(uint4*)&dst[c * 8 + 256] = *(const uint4*)&lds[r * 520 + c * 8 + 256];
    } else {
        // ---- B-pack: rows r0..r0+31 (r = i*8+y), transpose [k][r] -> [r][k] ----
        const int r0 = (b - 512) * 32;
        const int r4 = (t & 7) * 4;
        const int kq = t >> 3;                  // 0..31
        const float pa = Pa[(r0 + r4) >> 3];
        #pragma unroll
        for (int p = 0; p < 16; ++p) {
            const int k = p * 32 + kq;
            const float4 bv = *(const float4*)(B + (size_t)k * 4096 + r0 + r4);
            lds[(r4 + 0) * 520 + k] = f2bf(bv.x * pa);
            lds[(r4 + 1) * 520 + k] = f2bf(bv.y * pa);
            lds[(r4 + 2) * 520 + k] = f2bf(bv.z * pa);
            lds[(r4 + 3) * 520 + k] = f2bf(bv.w * pa);
        }
        __syncthreads();
        const int r = t >> 3;                   // 0..31
        const int c0 = t & 7;
        unsigned short* dst = Bop + (size_t)(r0 + r) * KD;
        #pragma unroll
        for (int p = 0; p < 8; ++p) {
            const int c = c0 + p * 8;
            *(uint4*)&dst[c * 8] = *(const uint4*)&lds[r * 520 + c * 8];
        }
    }
}

// ---------------------------------------------------------------------------
// One 4096x4096x512 bf16 GEMM (1024 blocks of 128x128, BK=32, XOR-swizzled
// LDS staging -> conflict-free frag reads) + fused C-contraction epilogue
// (8 KB C patch per block, C read once globally) + last-block finalize.
// NOTE: no min-occupancy launch_bounds clause — r5's (256,3) capped VGPR at
// 84 and spilled the accumulators to scratch (WRITE_SIZE 17.4 MB, 189 us).
// ---------------------------------------------------------------------------
__global__ __launch_bounds__(256) void gemm_kernel(
        const float* __restrict__ yp, const float* __restrict__ yt,
        const unsigned short* __restrict__ Aop,
        const unsigned short* __restrict__ Bop,
        float* __restrict__ part, unsigned int* __restrict__ counter,
        float* __restrict__ out) {

    __shared__ union {
        unsigned short stage[2][128 * 32];   // 16 KB total
        float red[4 * 512];                  // 8 KB per-wave output partials
    } sh;
    __shared__ int is_last;
    __shared__ float kred[4];

    const int bid = blockIdx.x;
    const int s8 = bid & 7;
    const int rr_ = bid >> 3;
    const int bm = ((s8 & 3) << 3) | (rr_ & 7);    // 0..31
    const int bn = ((s8 >> 2) << 4) | (rr_ >> 3);  // 0..31
    const int m0 = bm * 128;
    const int n0 = bn * 128;

    const int t = threadIdx.x;
    const int w = t >> 6;
    const int l = t & 63;
    const int wm = w >> 1, wn = w & 1;
    const int lm = l & 15, quad = l >> 4;

    // staging: lane l -> slot (row=l>>2, chunk=l&3); fetch global chunk
    // (l&3)^((l>>3)&3) so slot (r,c) holds global chunk c^((r>>1)&3).
    const int srow = l >> 2;
    const int gch = (l & 3) ^ ((l >> 3) & 3);
    // frag read: global chunk `quad` for row lm lives in slot quad^((lm>>1)&3)
    const int rch = quad ^ ((lm >> 1) & 3);

    v4f acc[4][4];
    #pragma unroll
    for (int mt = 0; mt < 4; ++mt)
        #pragma unroll
        for (int nt = 0; nt < 4; ++nt)
            acc[mt][nt] = (v4f){0.f, 0.f, 0.f, 0.f};

    const unsigned short* Ab = Aop + (size_t)m0 * KD + gch * 8;
    const unsigned short* Bb = Bop + (size_t)n0 * KD + gch * 8;

    for (int kt = 0; kt < 16; ++kt) {
        const int kb = kt * 32;
        #pragma unroll
        for (int a = 0; a < 2; ++a) {
            const int row = w * 32 + a * 16;
            async16(Ab + (size_t)(row + srow) * KD + kb, &sh.stage[0][row * 32]);
            async16(Bb + (size_t)(row + srow) * KD + kb, &sh.stage[1][row * 32]);
        }
        __syncthreads();

        v8s aF[4], bF[4];
        #pragma unroll
        for (int mt = 0; mt < 4; ++mt)
            aF[mt] = *(const v8s*)&sh.stage[0][(wm * 64 + mt * 16 + lm) * 32 + rch * 8];
        #pragma unroll
        for (int nt = 0; nt < 4; ++nt)
            bF[nt] = *(const v8s*)&sh.stage[1][(wn * 64 + nt * 16 + lm) * 32 + rch * 8];
        #pragma unroll
        for (int mt = 0; mt < 4; ++mt)
            #pragma unroll
            for (int nt = 0; nt < 4; ++nt)
                acc[mt][nt] = __builtin_amdgcn_mfma_f32_16x16x32_bf16(
                    aF[mt], bF[nt], acc[mt][nt], 0, 0, 0);
        __syncthreads();
    }

    // ---- epilogue (validated in r5) ----
    // M = m0 + wm*64 + mt*16 + quad*4 + rr -> x=(quad&1)*4+rr, j=M>>3
    // N = n0 + wn*64 + nt*16 + lm         -> y=lm&7,          i=N>>3
    const float* Cbase = yp + 3 * KD + 2 * (size_t)SZ;
    const int jA = bm * 16 + wm * 8 + (quad >> 1);   // + mt*2
    const int iA = bn * 16 + wn * 8 + (lm >> 3);     // + nt*2
    const int xpar = quad & 1;
    const int yv = lm & 7;

    #pragma unroll
    for (int zh = 0; zh < 2; ++zh) {
        v4f pacc[4];
        #pragma unroll
        for (int rr = 0; rr < 4; ++rr) pacc[rr] = (v4f){0.f, 0.f, 0.f, 0.f};

        #pragma unroll
        for (int mt = 0; mt < 4; ++mt) {
            #pragma unroll
            for (int nt = 0; nt < 4; ++nt) {
                const int i = iA + nt * 2;
                const int j = jA + mt * 2;
                const float4 cv = *(const float4*)(Cbase + (size_t)i * 4096 + j * 8 + zh * 4);
                #pragma unroll
                for (int rr = 0; rr < 4; ++rr) {
                    const float tv = acc[mt][nt][rr];
                    pacc[rr][0] += tv * cv.x;
                    pacc[rr][1] += tv * cv.y;
                    pacc[rr][2] += tv * cv.z;
                    pacc[rr][3] += tv * cv.w;
                }
            }
        }
        #pragma unroll
        for (int rr = 0; rr < 4; ++rr) {
            #pragma unroll
            for (int q = 0; q < 4; ++q) {
                float v = pacc[rr][q];
                v += __shfl_xor(v, 8, 64);
                v += __shfl_xor(v, 32, 64);
                pacc[rr][q] = v;
            }
        }
        if ((l & 40) == 0) {   // rep lanes: bits 3,5 clear
            #pragma unroll
            for (int rr = 0; rr < 4; ++rr) {
                const int x = xpar * 4 + rr;
                *(float4*)&sh.red[w * 512 + x * 64 + yv * 8 + zh * 4] =
                    make_float4(pacc[rr][0], pacc[rr][1], pacc[rr][2], pacc[rr][3]);
            }
        }
    }
    __syncthreads();
    #pragma unroll
    for (int h = 0; h < 2; ++h) {
        const int o = t + h * 256;
        const float sv = sh.red[o] + sh.red[512 + o] + sh.red[1024 + o] + sh.red[1536 + o];
        atomicAdd(&part[s8 * 512 + o], sv);
    }

    // ---- last-block finalize ----
    __threadfence();
    __syncthreads();
    if (t == 0) {
        const unsigned int old = atomicAdd(counter, 1u);
        is_last = (old == 1023u);
    }
    __syncthreads();
    if (is_last) {
        float term = 0.f;
        #pragma unroll
        for (int h = 0; h < 2; ++h) {
            const int o = t + h * 256;
            float p = 0.f;
            #pragma unroll
            for (int p8 = 0; p8 < 8; ++p8)
                p += atomicAdd(&part[p8 * 512 + o], 0.0f);   // coherent read
            out[1 + o] = p;
            const float ytv = yt[o];
            const float pc = fminf(fmaxf(p, 1e-10f), 1.0f);
            term += ytv * (logf(ytv + 1e-10f) - logf(pc));
        }
        for (int off = 32; off > 0; off >>= 1)
            term += __shfl_xor(term, off, 64);
        if (l == 0) kred[w] = term;
        __syncthreads();
        if (t == 0)
            out[0] = kred[0] + kred[1] + kred[2] + kred[3];
    }
}

extern "C" void kernel_launch(void* const* d_in, const int* in_sizes, int n_in,
                              void* d_out, int out_size, void* d_ws, size_t ws_size,
                              hipStream_t stream) {
    const float* yp = (const float*)d_in[0];
    const float* yt = (const float*)d_in[1];
    float* out = (float*)d_out;

    unsigned short* Aop = (unsigned short*)d_ws;               // 4 MB
    unsigned short* Bop = Aop + (size_t)NR * KD;               // 4 MB
    float* part = (float*)(Bop + (size_t)NR * KD);             // 8x512 floats
    unsigned int* counter = (unsigned int*)(part + 8 * 512);

    pack_kernel<<<640, 256, 0, stream>>>(yp, Aop, Bop, part, counter);
    gemm_kernel<<<1024, 256, 0, stream>>>(yp, yt, Aop, Bop, part, counter, out);
}